// Round 1
// 1383.705 us; speedup vs baseline: 1.1464x; 1.1464x over previous
//
#include <hip/hip_runtime.h>
#include <stdint.h>

// Problem constants (fixed by reference: B=4, S=2048, IN=4096, OUT=16384)
#define M_ROWS 8192     // B*S
#define N_COLS 16384    // OUT
#define K_ELEMS 4096    // IN
#define KW 128          // K in u32 words (4096/32) -- legacy popc path
#define LDS_STRIDE 20   // legacy popc path

// ============================================================================
// i8 MFMA path
// ============================================================================
typedef int i32x4  __attribute__((ext_vector_type(4)));
typedef int i32x16 __attribute__((ext_vector_type(16)));

typedef const __attribute__((address_space(1))) void* gptr_t;
typedef __attribute__((address_space(3))) void*       lptr_t;

__device__ __forceinline__ void gload_lds16(const void* g, void* l) {
    // 16B-wide async global->LDS. LDS dest = wave-uniform base + lane*16.
    __builtin_amdgcn_global_load_lds((gptr_t)g, (lptr_t)l, 16, 0, 0);
}

// ---- sign converts: fp32 -> int8 in {+1 (0x01), -1 (0xFF)} -----------------
__global__ void conv_x_i8(const float4* __restrict__ x, uint32_t* __restrict__ o,
                          int n4) {
    int i = blockIdx.x * blockDim.x + threadIdx.x;
    int st = gridDim.x * blockDim.x;
    for (; i < n4; i += st) {
        float4 v = x[i];
        uint32_t b0 = (v.x >= 0.0f) ? 0x01u : 0xFFu;
        uint32_t b1 = (v.y >= 0.0f) ? 0x01u : 0xFFu;
        uint32_t b2 = (v.z >= 0.0f) ? 0x01u : 0xFFu;
        uint32_t b3 = (v.w >= 0.0f) ? 0x01u : 0xFFu;
        o[i] = b0 | (b1 << 8) | (b2 << 16) | (b3 << 24);
    }
}

__global__ void conv_w_i8(const float4* __restrict__ w, const float* __restrict__ thr,
                          uint32_t* __restrict__ o, int n4) {
    int i = blockIdx.x * blockDim.x + threadIdx.x;
    int st = gridDim.x * blockDim.x;
    for (; i < n4; i += st) {
        float t = thr[i >> 10];          // 1024 float4 per 4096-elem row
        float4 v = w[i];
        uint32_t b0 = (v.x - t >= 0.0f) ? 0x01u : 0xFFu;
        uint32_t b1 = (v.y - t >= 0.0f) ? 0x01u : 0xFFu;
        uint32_t b2 = (v.z - t >= 0.0f) ? 0x01u : 0xFFu;
        uint32_t b3 = (v.w - t >= 0.0f) ? 0x01u : 0xFFu;
        o[i] = b0 | (b1 << 8) | (b2 << 16) | (b3 << 24);
    }
}

// ---- i8 MFMA GEMM: out[m][n] = dot(A[m,:], B[n,:]) * scale ------------------
// 128x128 tile, BK=64 bytes, 256 threads = 4 waves (2x2), each wave computes a
// 64x64 sub-tile as 2x2 mfma_i32_32x32x32_i8 accumulators.
//
// LDS layout: [row][4 x 16B k-slots], 64B rows, with an XOR involution on the
// slot index (slot ^= (row>>1)&3). Both the global-source addresses for
// global_load_lds (linear LDS dest) and the ds_read addresses apply the SAME
// involution (rule: both-sides-or-neither). This makes each wave64
// ds_read_b128 spread exactly 8 lanes per 4-bank group = BW-minimal, zero
// excess bank conflict.
__launch_bounds__(256, 3)
__global__ void bgemm_i8(const char* __restrict__ A,   // [M][K] i8 +/-1
                         const char* __restrict__ B,   // [N][K] i8 +/-1
                         const float* __restrict__ shift,
                         float* __restrict__ out) {
    __shared__ __align__(16) char As[2][128 * 64];   // 8KB per buffer
    __shared__ __align__(16) char Bs[2][128 * 64];

    const int tid  = threadIdx.x;
    const int lane = tid & 63;
    const int wid  = tid >> 6;        // 0..3
    const int wx   = wid & 1;         // N half of wave
    const int wy   = wid >> 1;        // M half of wave
    const int bm   = blockIdx.y * 128;
    const int bn   = blockIdx.x * 128;

    // ---- staging descriptors: each wave stages 2 chunks (1KB) of A and of B
    const char* gA[2];
    const char* gB[2];
    int lofs[2];
    #pragma unroll
    for (int j = 0; j < 2; ++j) {
        int c  = wid * 2 + j;         // chunk 0..7 (16 rows each)
        int li = c * 64 + lane;       // linear 16B slot 0..511
        int r  = li >> 2;             // tile row 0..127
        int s  = (li & 3) ^ ((r >> 1) & 3);   // pre-swizzled k-slot
        gA[j]   = A + (size_t)(bm + r) * K_ELEMS + s * 16;
        gB[j]   = B + (size_t)(bn + r) * K_ELEMS + s * 16;
        lofs[j] = c * 1024;
    }

    // ---- fragment LDS byte offsets (loop-invariant, swizzled)
    const int l31 = lane & 31, hi = lane >> 5;
    int aOff[2][2], bOff[2][2];       // [m/n tile][k-step]
    #pragma unroll
    for (int t = 0; t < 2; ++t) {
        int Rm = wy * 64 + t * 32 + l31;
        int Rn = wx * 64 + t * 32 + l31;
        #pragma unroll
        for (int ks = 0; ks < 2; ++ks) {
            aOff[t][ks] = Rm * 64 + (((ks * 2 + hi) ^ ((Rm >> 1) & 3)) << 4);
            bOff[t][ks] = Rn * 64 + (((ks * 2 + hi) ^ ((Rn >> 1) & 3)) << 4);
        }
    }

    i32x16 acc[2][2] = {};

    // prologue: stage K-tile 0 into buffer 0
    #pragma unroll
    for (int j = 0; j < 2; ++j) {
        gload_lds16(gA[j], &As[0][lofs[j]]);
        gload_lds16(gB[j], &Bs[0][lofs[j]]);
    }
    __syncthreads();   // compiler drains vmcnt(0) before barrier

    const int NT = K_ELEMS / 64;      // 64 K-tiles
    #pragma unroll 2
    for (int t = 0; t < NT; ++t) {
        const int cur = t & 1;
        // issue next-tile staging BEFORE compute (min-2-phase overlap)
        if (t + 1 < NT) {
            const int kb = (t + 1) * 64;
            #pragma unroll
            for (int j = 0; j < 2; ++j) {
                gload_lds16(gA[j] + kb, &As[cur ^ 1][lofs[j]]);
                gload_lds16(gB[j] + kb, &Bs[cur ^ 1][lofs[j]]);
            }
        }
        #pragma unroll
        for (int ks = 0; ks < 2; ++ks) {
            i32x4 a0 = *(const i32x4*)(&As[cur][aOff[0][ks]]);
            i32x4 a1 = *(const i32x4*)(&As[cur][aOff[1][ks]]);
            i32x4 b0 = *(const i32x4*)(&Bs[cur][bOff[0][ks]]);
            i32x4 b1 = *(const i32x4*)(&Bs[cur][bOff[1][ks]]);
            acc[0][0] = __builtin_amdgcn_mfma_i32_32x32x32_i8(a0, b0, acc[0][0], 0, 0, 0);
            acc[0][1] = __builtin_amdgcn_mfma_i32_32x32x32_i8(a0, b1, acc[0][1], 0, 0, 0);
            acc[1][0] = __builtin_amdgcn_mfma_i32_32x32x32_i8(a1, b0, acc[1][0], 0, 0, 0);
            acc[1][1] = __builtin_amdgcn_mfma_i32_32x32x32_i8(a1, b1, acc[1][1], 0, 0, 0);
        }
        // one barrier per tile: implicit vmcnt(0) drain => next buffer ready,
        // and everyone is done reading cur before it is overwritten.
        __syncthreads();
    }

    // ---- epilogue: out = acc * 2^round(clip(shift,-8,0)), exact ----
    float sp    = shift[0];
    float rr    = rintf(fminf(fmaxf(sp, -8.0f), 0.0f));   // round-half-even
    float scale = exp2f(rr);

    #pragma unroll
    for (int mt = 0; mt < 2; ++mt) {
        #pragma unroll
        for (int nt = 0; nt < 2; ++nt) {
            #pragma unroll
            for (int reg = 0; reg < 16; ++reg) {
                // C/D layout 32x32: col=lane&31, row=(reg&3)+8*(reg>>2)+4*(lane>>5)
                int row = bm + wy * 64 + mt * 32 + (reg & 3) + 8 * (reg >> 2) + 4 * hi;
                int col = bn + wx * 64 + nt * 32 + l31;
                out[(size_t)row * N_COLS + col] = scale * (float)acc[mt][nt][reg];
            }
        }
    }
}

// ============================================================================
// Legacy popc path (fallback if workspace < 96MB)
// ============================================================================
__global__ void pack_x_kernel(const float4* __restrict__ x,
                              uint64_t* __restrict__ out, int nwaves) {
    int lane = threadIdx.x & 63;
    int gw = (blockIdx.x * blockDim.x + threadIdx.x) >> 6;
    int stride = (gridDim.x * blockDim.x) >> 6;
    for (int w = gw; w < nwaves; w += stride) {
        float4 v = x[(size_t)w * 64 + lane];
        uint64_t m0 = __ballot(v.x < 0.0f);
        uint64_t m1 = __ballot(v.y < 0.0f);
        uint64_t m2 = __ballot(v.z < 0.0f);
        uint64_t m3 = __ballot(v.w < 0.0f);
        uint64_t sel = (lane == 0) ? m0 : (lane == 1) ? m1 : (lane == 2) ? m2 : m3;
        if (lane < 4) out[(size_t)w * 4 + lane] = sel;
    }
}

__global__ void pack_w_kernel(const float4* __restrict__ wgt,
                              const float* __restrict__ thr,
                              uint64_t* __restrict__ out, int nwaves) {
    int lane = threadIdx.x & 63;
    int gw = (blockIdx.x * blockDim.x + threadIdx.x) >> 6;
    int stride = (gridDim.x * blockDim.x) >> 6;
    for (int w = gw; w < nwaves; w += stride) {
        size_t f4 = (size_t)w * 64 + lane;
        float t = thr[f4 >> 10];
        float4 v = wgt[f4];
        uint64_t m0 = __ballot(v.x - t < 0.0f);
        uint64_t m1 = __ballot(v.y - t < 0.0f);
        uint64_t m2 = __ballot(v.z - t < 0.0f);
        uint64_t m3 = __ballot(v.w - t < 0.0f);
        uint64_t sel = (lane == 0) ? m0 : (lane == 1) ? m1 : (lane == 2) ? m2 : m3;
        if (lane < 4) out[(size_t)w * 4 + lane] = sel;
    }
}

__launch_bounds__(256, 2)
__global__ void bgemm_kernel(const uint32_t* __restrict__ A,
                             const uint32_t* __restrict__ B,
                             const float* __restrict__ shift,
                             float* __restrict__ out) {
    __shared__ uint32_t As[128 * LDS_STRIDE];
    __shared__ uint32_t Bs[128 * LDS_STRIDE];

    const int tid = threadIdx.x;
    const int tx = tid & 15;
    const int ty = tid >> 4;
    const int bm = blockIdx.y * 128;
    const int bn = blockIdx.x * 128;

    const int r0 = tid >> 2, g0 = tid & 3;
    const int r1 = (tid + 256) >> 2, g1 = tid & 3;

    uint32_t acc[8][8];
    #pragma unroll
    for (int i = 0; i < 8; ++i)
        #pragma unroll
        for (int j = 0; j < 8; ++j) acc[i][j] = 0u;

    uint4 pa0, pa1, pb0, pb1;
    pa0 = *(const uint4*)&A[(size_t)(bm + r0) * KW + 0 + g0 * 4];
    pa1 = *(const uint4*)&A[(size_t)(bm + r1) * KW + 0 + g1 * 4];
    pb0 = *(const uint4*)&B[(size_t)(bn + r0) * KW + 0 + g0 * 4];
    pb1 = *(const uint4*)&B[(size_t)(bn + r1) * KW + 0 + g1 * 4];

    for (int kb = 0; kb < KW; kb += 16) {
        *(uint4*)&As[r0 * LDS_STRIDE + g0 * 4] = pa0;
        *(uint4*)&As[r1 * LDS_STRIDE + g1 * 4] = pa1;
        *(uint4*)&Bs[r0 * LDS_STRIDE + g0 * 4] = pb0;
        *(uint4*)&Bs[r1 * LDS_STRIDE + g1 * 4] = pb1;
        __syncthreads();

        if (kb + 16 < KW) {
            int kn = kb + 16;
            pa0 = *(const uint4*)&A[(size_t)(bm + r0) * KW + kn + g0 * 4];
            pa1 = *(const uint4*)&A[(size_t)(bm + r1) * KW + kn + g1 * 4];
            pb0 = *(const uint4*)&B[(size_t)(bn + r0) * KW + kn + g0 * 4];
            pb1 = *(const uint4*)&B[(size_t)(bn + r1) * KW + kn + g1 * 4];
        }

        #pragma unroll
        for (int g = 0; g < 4; ++g) {
            uint4 b[8];
            #pragma unroll
            for (int c = 0; c < 8; ++c)
                b[c] = *(const uint4*)&Bs[(tx + 16 * c) * LDS_STRIDE + g * 4];
            #pragma unroll
            for (int r = 0; r < 8; ++r) {
                uint4 a = *(const uint4*)&As[(ty + 16 * r) * LDS_STRIDE + g * 4];
                #pragma unroll
                for (int c = 0; c < 8; ++c) {
                    acc[r][c] += __popc(a.x ^ b[c].x);
                    acc[r][c] += __popc(a.y ^ b[c].y);
                    acc[r][c] += __popc(a.z ^ b[c].z);
                    acc[r][c] += __popc(a.w ^ b[c].w);
                }
            }
        }
        __syncthreads();
    }

    float sp = shift[0];
    float rr = rintf(fminf(fmaxf(sp, -8.0f), 0.0f));
    float scale = exp2f(rr);
    float base = (float)K_ELEMS * scale;
    float m2s = -2.0f * scale;

    #pragma unroll
    for (int i = 0; i < 8; ++i) {
        size_t rowoff = (size_t)(bm + ty + 16 * i) * (size_t)N_COLS + (size_t)bn;
        #pragma unroll
        for (int j = 0; j < 8; ++j) {
            out[rowoff + tx + 16 * j] = fmaf(m2s, (float)acc[i][j], base);
        }
    }
}

// ============================================================================
extern "C" void kernel_launch(void* const* d_in, const int* in_sizes, int n_in,
                              void* d_out, int out_size, void* d_ws, size_t ws_size,
                              hipStream_t stream) {
    const float* x     = (const float*)d_in[0];   // [4,2048,4096] fp32
    const float* w     = (const float*)d_in[1];   // [16384,4096] fp32
    const float* thr   = (const float*)d_in[2];   // [16384,1] fp32
    const float* shift = (const float*)d_in[3];   // scalar fp32
    float* out = (float*)d_out;

    const size_t A_BYTES = (size_t)M_ROWS * K_ELEMS;   // 32 MB
    const size_t B_BYTES = (size_t)N_COLS * K_ELEMS;   // 64 MB

    if (ws_size >= A_BYTES + B_BYTES) {
        // ---- i8 MFMA path ----
        char* Ai8 = (char*)d_ws;
        char* Bi8 = Ai8 + A_BYTES;

        conv_x_i8<<<2048, 256, 0, stream>>>((const float4*)x, (uint32_t*)Ai8,
                                            (int)(A_BYTES / 4));
        conv_w_i8<<<2048, 256, 0, stream>>>((const float4*)w, thr, (uint32_t*)Bi8,
                                            (int)(B_BYTES / 4));

        dim3 grid(N_COLS / 128, M_ROWS / 128);   // (128, 64) = 8192 blocks
        bgemm_i8<<<grid, 256, 0, stream>>>(Ai8, Bi8, shift, out);
    } else {
        // ---- legacy popc path (small workspace) ----
        uint32_t* Apk = (uint32_t*)d_ws;
        uint32_t* Bpk = Apk + (size_t)M_ROWS * KW;

        pack_x_kernel<<<2048, 256, 0, stream>>>((const float4*)x, (uint64_t*)Apk,
                                                (M_ROWS * K_ELEMS) / 256);
        pack_w_kernel<<<4096, 256, 0, stream>>>((const float4*)w, thr, (uint64_t*)Bpk,
                                                (N_COLS * K_ELEMS) / 256);

        dim3 grid(N_COLS / 128, M_ROWS / 128);
        bgemm_kernel<<<grid, 256, 0, stream>>>(Apk, Bpk, shift, out);
    }
}